// Round 14
// baseline (436.832 us; speedup 1.0000x reference)
//
#include <hip/hip_runtime.h>
#include <stdint.h>

typedef __bf16 bf16x8 __attribute__((ext_vector_type(8)));
typedef float f32x4 __attribute__((ext_vector_type(4)));
typedef uint16_t u16x4 __attribute__((ext_vector_type(4)));
typedef uint16_t u16x8 __attribute__((ext_vector_type(8)));

#define LOG2E 1.4426950408889634f

__device__ __forceinline__ uint16_t f2bf(float f) {
  union { float f; uint32_t u; } v; v.f = f;
  return (uint16_t)((v.u + 0x7fffu + ((v.u >> 16) & 1u)) >> 16);
}

__device__ __forceinline__ void gload_lds16(const void* g, void* l) {
  __builtin_amdgcn_global_load_lds(
      (const __attribute__((address_space(1))) void*)g,
      (__attribute__((address_space(3))) void*)l, 16, 0, 0);
}

__device__ __forceinline__ f32x4 mfma16(bf16x8 a, bf16x8 b, f32x4 c) {
  return __builtin_amdgcn_mfma_f32_16x16x32_bf16(a, b, c, 0, 0, 0);
}

// ---------------- LayerNorm: x (2048x2048 f32) -> h (bf16) ----------------
__global__ __launch_bounds__(256) void ln_kernel(const float* __restrict__ x,
                                                 const float* __restrict__ g,
                                                 const float* __restrict__ bta,
                                                 uint16_t* __restrict__ h) {
  const int row = blockIdx.x;
  const int t = threadIdx.x;
  const float* xr = x + (size_t)row * 2048 + t * 8;
  float4 v0 = *(const float4*)xr;
  float4 v1 = *(const float4*)(xr + 4);
  float s = v0.x + v0.y + v0.z + v0.w + v1.x + v1.y + v1.z + v1.w;
  float q = v0.x*v0.x + v0.y*v0.y + v0.z*v0.z + v0.w*v0.w
          + v1.x*v1.x + v1.y*v1.y + v1.z*v1.z + v1.w*v1.w;
  #pragma unroll
  for (int m = 1; m < 64; m <<= 1) {
    s += __shfl_xor(s, m);
    q += __shfl_xor(q, m);
  }
  __shared__ float ps[4], pq[4];
  const int wid = t >> 6, lane = t & 63;
  if (lane == 0) { ps[wid] = s; pq[wid] = q; }
  __syncthreads();
  s = ps[0] + ps[1] + ps[2] + ps[3];
  q = pq[0] + pq[1] + pq[2] + pq[3];
  const float mu = s * (1.0f / 2048.0f);
  const float var = q * (1.0f / 2048.0f) - mu * mu;
  const float rs = rsqrtf(var + 1e-5f);
  float4 w0 = *(const float4*)(g + t * 8);
  float4 w1 = *(const float4*)(g + t * 8 + 4);
  float4 b0 = *(const float4*)(bta + t * 8);
  float4 b1 = *(const float4*)(bta + t * 8 + 4);
  u16x8 o;
  o[0] = f2bf((v0.x - mu) * rs * w0.x + b0.x);
  o[1] = f2bf((v0.y - mu) * rs * w0.y + b0.y);
  o[2] = f2bf((v0.z - mu) * rs * w0.z + b0.z);
  o[3] = f2bf((v0.w - mu) * rs * w0.w + b0.w);
  o[4] = f2bf((v1.x - mu) * rs * w1.x + b1.x);
  o[5] = f2bf((v1.y - mu) * rs * w1.y + b1.y);
  o[6] = f2bf((v1.z - mu) * rs * w1.z + b1.z);
  o[7] = f2bf((v1.w - mu) * rs * w1.w + b1.w);
  *(u16x8*)(h + (size_t)row * 2048 + t * 8) = o;
}

// ------- transpose+convert: in (R x ldin f32) -> out (C x R bf16), tile 64x64
__global__ __launch_bounds__(256) void transpose_w(const float* __restrict__ in,
                                                   uint16_t* __restrict__ out,
                                                   int R, int ldin,
                                                   int scale_cols, float scale) {
  __shared__ uint16_t tile[64][65];
  const int c0 = blockIdx.x * 64;
  const int r0 = blockIdx.y * 64;
  const int t = threadIdx.x;
  const int cc = (t & 15) * 4;
  const int rb = t >> 4;
  #pragma unroll
  for (int p = 0; p < 4; ++p) {
    const int r = rb + p * 16;
    const float4 v = *(const float4*)(in + (size_t)(r0 + r) * ldin + c0 + cc);
    const float m0 = (c0 + cc + 0) < scale_cols ? scale : 1.0f;
    const float m1 = (c0 + cc + 1) < scale_cols ? scale : 1.0f;
    const float m2 = (c0 + cc + 2) < scale_cols ? scale : 1.0f;
    const float m3 = (c0 + cc + 3) < scale_cols ? scale : 1.0f;
    tile[r][cc + 0] = f2bf(v.x * m0);
    tile[r][cc + 1] = f2bf(v.y * m1);
    tile[r][cc + 2] = f2bf(v.z * m2);
    tile[r][cc + 3] = f2bf(v.w * m3);
  }
  __syncthreads();
  #pragma unroll
  for (int p = 0; p < 4; ++p) {
    const int oc = rb + p * 16;
    u16x4 ov;
    ov.x = tile[cc + 0][oc];
    ov.y = tile[cc + 1][oc];
    ov.z = tile[cc + 2][oc];
    ov.w = tile[cc + 3][oc];
    *(u16x4*)(out + (size_t)(c0 + oc) * R + r0 + cc) = ov;
  }
}

// ------- transpose V slab of res (cols 4096..6143) -> vt (2048 x 2048 bf16)
__global__ __launch_bounds__(256) void transpose_v(const uint16_t* __restrict__ res,
                                                   uint16_t* __restrict__ vt) {
  __shared__ uint16_t tile[64][65];
  const int c0 = blockIdx.x * 64;
  const int r0 = blockIdx.y * 64;
  const int t = threadIdx.x;
  const int cc = (t & 15) * 4;
  const int rb = t >> 4;
  #pragma unroll
  for (int p = 0; p < 4; ++p) {
    const int r = rb + p * 16;
    const u16x4 v = *(const u16x4*)(res + (size_t)(r0 + r) * 14336 + 4096 + c0 + cc);
    tile[r][cc + 0] = v.x;
    tile[r][cc + 1] = v.y;
    tile[r][cc + 2] = v.z;
    tile[r][cc + 3] = v.w;
  }
  __syncthreads();
  #pragma unroll
  for (int p = 0; p < 4; ++p) {
    const int oc = rb + p * 16;
    u16x4 ov;
    ov.x = tile[cc + 0][oc];
    ov.y = tile[cc + 1][oc];
    ov.z = tile[cc + 2][oc];
    ov.w = tile[cc + 3][oc];
    *(u16x4*)(vt + (size_t)(c0 + oc) * 2048 + r0 + cc) = ov;
  }
}

// ------- Square-block BT GEMM (GEMM1): C = A * B^T, BM=BN=256, BK=32.
// 8 waves (4M x 2N), wave C = 64x128 (acc[4][8], 128 AGPR). LDS 64KB
// (2 x 16KB x 2buf) -> 2 blocks/CU. Fragment reads per wave-K-tile:
// af[4]+bf[8] = 12 x ds_read_b128 feeding 32 MFMA -> ~500 B/MFMA total LDS
// traffic (vs r11's 704): predicted MfmaUtil ceiling ~46%.
// Sync skeleton = r11: ONE vmcnt(0)+barrier per K-tile, stage(t+1) full-tile
// lead, compiler-scheduled lgkmcnt, tail sched_barrier pins MFMAs in-tile.
__global__ __launch_bounds__(512, 2) void gemm_sq(
    const uint16_t* __restrict__ A, const uint16_t* __restrict__ B,
    uint16_t* __restrict__ C, int ldbK, int ldc, int nt) {
  __shared__ __attribute__((aligned(16))) uint16_t Alds[2][256 * 32];
  __shared__ __attribute__((aligned(16))) uint16_t Blds[2][256 * 32];
  const int bid = blockIdx.x;
  const int qx = gridDim.x >> 3;                       // grid % 8 == 0
  const int wg = (bid & 7) * qx + (bid >> 3);          // bijective XCD swizzle
  const int m0 = (wg & 7) << 8;                        // 8 M-tiles of 256
  const int n0 = (wg >> 3) << 8;                       // N-tiles of 256
  const int t = threadIdx.x, wid = t >> 6, lane = t & 63;
  const int wr = wid >> 1, wc = wid & 1;               // 4M x 2N wave grid

  f32x4 acc[4][8] = {};

  auto stage = [&](int tt) {
    const int kg = tt * 32;
    char* ab = (char*)Alds[tt & 1];
    char* bb = (char*)Blds[tt & 1];
    #pragma unroll
    for (int j = 0; j < 2; ++j) {                      // A: 1024 x 16B chunks
      const int ch = j * 512 + t;
      const int r = ch >> 2, s = ch & 3;
      gload_lds16(A + (size_t)(m0 + r) * 2048 + kg + ((s ^ ((r >> 1) & 3)) << 3),
                  ab + ch * 16);
    }
    #pragma unroll
    for (int j = 0; j < 2; ++j) {                      // B: 1024 x 16B chunks
      const int ch = j * 512 + t;
      const int r = ch >> 2, s = ch & 3;
      gload_lds16(B + (size_t)(n0 + r) * ldbK + kg + ((s ^ ((r >> 1) & 3)) << 3),
                  bb + ch * 16);
    }
  };

  stage(0);
  for (int tt = 0; tt < nt; ++tt) {
    const int buf = tt & 1;
    asm volatile("s_waitcnt vmcnt(0)" ::: "memory");   // stage(tt) landed
    __builtin_amdgcn_s_barrier();                      // publish DMA; buf^1 free
    __builtin_amdgcn_sched_barrier(0);
    if (tt + 1 < nt) stage(tt + 1);                    // full-tile lead
    const char* Ab = (const char*)Alds[buf];
    const char* Bb = (const char*)Blds[buf];
    bf16x8 bfr[8], af[4];
    #pragma unroll
    for (int n = 0; n < 8; ++n) {
      const int r = wc * 128 + n * 16 + (lane & 15);
      const int c = (lane >> 4) ^ ((r >> 1) & 3);
      bfr[n] = *(const bf16x8*)(Bb + r * 64 + c * 16);
    }
    #pragma unroll
    for (int m = 0; m < 4; ++m) {
      const int r = wr * 64 + m * 16 + (lane & 15);
      const int c = (lane >> 4) ^ ((r >> 1) & 3);
      af[m] = *(const bf16x8*)(Ab + r * 64 + c * 16);
    }
    #pragma unroll
    for (int m = 0; m < 4; ++m)
      #pragma unroll
      for (int n = 0; n < 8; ++n)
        acc[m][n] = mfma16(af[m], bfr[n], acc[m][n]);
    __builtin_amdgcn_sched_barrier(0);                 // pin MFMAs in-tile
  }

  #pragma unroll
  for (int m = 0; m < 4; ++m)
    #pragma unroll
    for (int n = 0; n < 8; ++n)
      #pragma unroll
      for (int r = 0; r < 4; ++r) {
        const int row = m0 + wr * 64 + m * 16 + (lane >> 4) * 4 + r;
        const int col = n0 + wc * 128 + n * 16 + (lane & 15);
        C[(size_t)row * ldc + col] = f2bf(acc[m][n][r]);
      }
}

// ------- Block-wide BT GEMM (r11, GEMM2): BM=128, BN=256, BK=32, 8 waves
// (2Mx4N), wave C = 64x64. LDS 48KB dbuf. r11 sync skeleton. Split-K fp32.
template <int CONCAT, int CF32>
__global__ __launch_bounds__(512, 2) void gemm_bw(
    const uint16_t* __restrict__ A0, const uint16_t* __restrict__ A1,
    const uint16_t* __restrict__ B, void* __restrict__ C0, void* __restrict__ C1,
    int ldbK, int ldc, int kchunk, int nt) {
  __shared__ __attribute__((aligned(16))) uint16_t Alds[2][128 * 32];
  __shared__ __attribute__((aligned(16))) uint16_t Blds[2][256 * 32];
  const int bid = blockIdx.x;
  const int qx = gridDim.x >> 3;
  const int wg = (bid & 7) * qx + (bid >> 3);          // bijective XCD swizzle
  const int m0 = (wg & 15) << 7;                       // 16 M-tiles of 128
  const int n0 = (wg >> 4) << 8;                       // N-tiles of 256
  const int sk = blockIdx.y;
  const int k0 = sk * kchunk;
  const int t = threadIdx.x, wid = t >> 6, lane = t & 63;
  const int wr = wid >> 2, wc = wid & 3;               // 2M x 4N wave grid

  f32x4 acc[4][4] = {};

  auto stage = [&](int tt) {
    const int kg = k0 + tt * 32;
    const uint16_t* As; int lda, kc;
    if (CONCAT && kg >= 2048) { As = A1; lda = 14336; kc = kg + 4096; }
    else                      { As = A0; lda = 2048;  kc = kg; }
    char* ab = (char*)Alds[tt & 1];
    char* bb = (char*)Blds[tt & 1];
    {                                                  // A: 512 x 16B chunks
      const int ch = t;
      const int r = ch >> 2, s = ch & 3;
      gload_lds16(As + (size_t)(m0 + r) * lda + kc + ((s ^ ((r >> 1) & 3)) << 3),
                  ab + ch * 16);
    }
    #pragma unroll
    for (int j = 0; j < 2; ++j) {                      // B: 1024 x 16B chunks
      const int ch = j * 512 + t;
      const int r = ch >> 2, s = ch & 3;
      gload_lds16(B + (size_t)(n0 + r) * ldbK + kg + ((s ^ ((r >> 1) & 3)) << 3),
                  bb + ch * 16);
    }
  };

  stage(0);
  for (int tt = 0; tt < nt; ++tt) {
    const int buf = tt & 1;
    asm volatile("s_waitcnt vmcnt(0)" ::: "memory");   // stage(tt) landed
    __builtin_amdgcn_s_barrier();                      // publish DMA; buf^1 free
    __builtin_amdgcn_sched_barrier(0);
    if (tt + 1 < nt) stage(tt + 1);                    // full-tile lead
    const char* Ab = (const char*)Alds[buf];
    const char* Bb = (const char*)Blds[buf];
    bf16x8 bfr[4], af[4];
    #pragma unroll
    for (int n = 0; n < 4; ++n) {
      const int r = wc * 64 + n * 16 + (lane & 15);
      const int c = (lane >> 4) ^ ((r >> 1) & 3);
      bfr[n] = *(const bf16x8*)(Bb + r * 64 + c * 16);
    }
    #pragma unroll
    for (int m = 0; m < 4; ++m) {
      const int r = wr * 64 + m * 16 + (lane & 15);
      const int c = (lane >> 4) ^ ((r >> 1) & 3);
      af[m] = *(const bf16x8*)(Ab + r * 64 + c * 16);
    }
    #pragma unroll
    for (int m = 0; m < 4; ++m)
      #pragma unroll
      for (int n = 0; n < 4; ++n)
        acc[m][n] = mfma16(af[m], bfr[n], acc[m][n]);
    __builtin_amdgcn_sched_barrier(0);                 // pin MFMAs in-tile
  }

  #pragma unroll
  for (int m = 0; m < 4; ++m)
    #pragma unroll
    for (int n = 0; n < 4; ++n)
      #pragma unroll
      for (int r = 0; r < 4; ++r) {
        const int row = m0 + wr * 64 + m * 16 + (lane >> 4) * 4 + r;
        const int col = n0 + wc * 64 + n * 16 + (lane & 15);
        if (CF32) {
          float* C = (sk == 0) ? (float*)C0
                               : ((float*)C1 + (size_t)(sk - 1) * 4194304ull);
          C[(size_t)row * ldc + col] = acc[m][n][r];
        } else {
          ((uint16_t*)C0)[(size_t)row * ldc + col] = f2bf(acc[m][n][r]);
        }
      }
}

// ------- out += p1 + p2 + p3 (fp32, 2048x2048 each) -------
__global__ __launch_bounds__(256) void reduce_add3(float* __restrict__ out,
                                                   const float* __restrict__ p) {
  const size_t i = ((size_t)blockIdx.x * 256 + threadIdx.x) * 4;
  float4 a = *(const float4*)(out + i);
  const float4 b = *(const float4*)(p + i);
  const float4 c = *(const float4*)(p + 4194304 + i);
  const float4 d = *(const float4*)(p + 8388608 + i);
  a.x += b.x + c.x + d.x;
  a.y += b.y + c.y + d.y;
  a.z += b.z + c.z + d.z;
  a.w += b.w + c.w + d.w;
  *(float4*)(out + i) = a;
}

// ------- causal flash attention, 3-ring K/V pipeline. Block: (xq, head).
// Complement-qt remap for load balance: co-resident pairs get qt and 15-qt.
__global__ __launch_bounds__(256, 2) void attn_kernel(const uint16_t* __restrict__ res,
                                                      const uint16_t* __restrict__ vt,
                                                      uint16_t* __restrict__ aout) {
  const int hh = blockIdx.y;
  const int qt = (hh < 16) ? blockIdx.x : 15 - blockIdx.x;
  const int q0 = qt * 128;
  const int t = threadIdx.x, wid = t >> 6, lane = t & 63;
  const int qw = q0 + wid * 32;
  __shared__ __attribute__((aligned(16))) uint16_t Klds[3][64 * 64];
  __shared__ __attribute__((aligned(16))) uint16_t Vlds[3][64 * 64];
  __shared__ __attribute__((aligned(16))) uint16_t Plds[4 * 32 * 64];
  char* pbase = (char*)Plds + wid * 4096;

  bf16x8 qf[2][2];
  #pragma unroll
  for (int m = 0; m < 2; ++m)
    #pragma unroll
    for (int ks = 0; ks < 2; ++ks)
      qf[m][ks] = *(const bf16x8*)(res + (size_t)(qw + m * 16 + (lane & 15)) * 14336
                                   + hh * 64 + ks * 32 + (lane >> 4) * 8);
  f32x4 O[2][4] = {};
  f32x4 mrun[2], lrun[2];
  #pragma unroll
  for (int m = 0; m < 2; ++m)
    #pragma unroll
    for (int r = 0; r < 4; ++r) { mrun[m][r] = -1e30f; lrun[m][r] = 0.0f; }

  auto stageKV = [&](int kt) {
    const int k0 = kt * 64;
    char* kb = (char*)Klds[kt % 3];
    char* vb = (char*)Vlds[kt % 3];
    #pragma unroll
    for (int i = 0; i < 2; ++i) {
      const int o = (wid * 2 + i) * 1024 + lane * 16;
      const int row = o >> 7;
      const int slot = (o >> 4) & 7;
      const int col = (slot ^ (row & 7)) << 3;
      gload_lds16(res + (size_t)(k0 + row) * 14336 + 2048 + hh * 64 + col,
                  kb + (wid * 2 + i) * 1024);
      gload_lds16(vt + (size_t)(hh * 64 + row) * 2048 + k0 + col,
                  vb + (wid * 2 + i) * 1024);
    }
  };

  const int nkt = qt * 2 + 2;
  stageKV(0);
  if (1 < nkt) stageKV(1);
  for (int kt = 0; kt < nkt; ++kt) {
    const int k0 = kt * 64;
    if (kt + 1 < nkt) { asm volatile("s_waitcnt vmcnt(4)" ::: "memory"); }
    else              { asm volatile("s_waitcnt vmcnt(0)" ::: "memory"); }
    __builtin_amdgcn_s_barrier();
    __builtin_amdgcn_sched_barrier(0);
    if (kt + 2 < nkt) stageKV(kt + 2);
    if (k0 <= qw + 31) {
      const char* Kb = (const char*)Klds[kt % 3];
      const char* Vb = (const char*)Vlds[kt % 3];
      f32x4 s[2][4] = {};
      #pragma unroll
      for (int ks = 0; ks < 2; ++ks) {
        bf16x8 kf[4];
        #pragma unroll
        for (int n = 0; n < 4; ++n) {
          const int row = n * 16 + (lane & 15);
          const int slot = (ks * 4 + (lane >> 4)) ^ (row & 7);
          kf[n] = *(const bf16x8*)(Kb + row * 128 + slot * 16);
        }
        #pragma unroll
        for (int m = 0; m < 2; ++m)
          #pragma unroll
          for (int n = 0; n < 4; ++n)
            s[m][n] = mfma16(qf[m][ks], kf[n], s[m][n]);
      }
      if (k0 + 63 > qw) {
        #pragma unroll
        for (int m = 0; m < 2; ++m)
          #pragma unroll
          for (int n = 0; n < 4; ++n)
            #pragma unroll
            for (int r = 0; r < 4; ++r) {
              const int key = k0 + n * 16 + (lane & 15);
              const int qr = qw + m * 16 + (lane >> 4) * 4 + r;
              if (key > qr) s[m][n][r] = -1e30f;
            }
      }
      #pragma unroll
      for (int m = 0; m < 2; ++m) {
        f32x4 tmax = s[m][0];
        #pragma unroll
        for (int n = 1; n < 4; ++n)
          #pragma unroll
          for (int r = 0; r < 4; ++r) tmax[r] = fmaxf(tmax[r], s[m][n][r]);
        #pragma unroll
        for (int msk = 1; msk < 16; msk <<= 1)
          #pragma unroll
          for (int r = 0; r < 4; ++r) tmax[r] = fmaxf(tmax[r], __shfl_xor(tmax[r], msk));
        f32x4 newm, sc;
        #pragma unroll
        for (int r = 0; r < 4; ++r) {
          newm[r] = fmaxf(mrun[m][r], tmax[r]);
          sc[r] = exp2f((mrun[m][r] - newm[r]) * LOG2E);
          mrun[m][r] = newm[r];
        }
        f32x4 psum;
        #pragma unroll
        for (int r = 0; r < 4; ++r) psum[r] = 0.0f;
        #pragma unroll
        for (int n = 0; n < 4; ++n)
          #pragma unroll
          for (int r = 0; r < 4; ++r) {
            const float p = exp2f((s[m][n][r] - newm[r]) * LOG2E);
            s[m][n][r] = p;
            psum[r] += p;
          }
        #pragma unroll
        for (int msk = 1; msk < 16; msk <<= 1)
          #pragma unroll
          for (int r = 0; r < 4; ++r) psum[r] += __shfl_xor(psum[r], msk);
        #pragma unroll
        for (int r = 0; r < 4; ++r) lrun[m][r] = lrun[m][r] * sc[r] + psum[r];
        #pragma unroll
        for (int d = 0; d < 4; ++d)
          #pragma unroll
          for (int r = 0; r < 4; ++r) O[m][d][r] *= sc[r];
        #pragma unroll
        for (int n = 0; n < 4; ++n)
          #pragma unroll
          for (int r = 0; r < 4; ++r) {
            const int prow = m * 16 + (lane >> 4) * 4 + r;
            const int pcol = n * 16 + (lane & 15);
            *(uint16_t*)(pbase + prow * 128 + (((pcol >> 3) ^ (prow & 7)) << 4)
                         + (pcol & 7) * 2) = f2bf(s[m][n][r]);
          }
      }
      asm volatile("s_waitcnt lgkmcnt(0)" ::: "memory");
      __builtin_amdgcn_sched_barrier(0);
      #pragma unroll
      for (int ks = 0; ks < 2; ++ks) {
        bf16x8 pa[2], vf[4];
        #pragma unroll
        for (int m = 0; m < 2; ++m) {
          const int row = m * 16 + (lane & 15);
          const int slot = (ks * 4 + (lane >> 4)) ^ (row & 7);
          pa[m] = *(const bf16x8*)(pbase + row * 128 + slot * 16);
        }
        #pragma unroll
        for (int d = 0; d < 4; ++d) {
          const int row = d * 16 + (lane & 15);
          const int slot = (ks * 4 + (lane >> 4)) ^ (row & 7);
          vf[d] = *(const bf16x8*)(Vb + row * 128 + slot * 16);
        }
        #pragma unroll
        for (int m = 0; m < 2; ++m)
          #pragma unroll
          for (int d = 0; d < 4; ++d)
            O[m][d] = mfma16(pa[m], vf[d], O[m][d]);
      }
    }
  }
  #pragma unroll
  for (int m = 0; m < 2; ++m) {
    f32x4 inv;
    #pragma unroll
    for (int r = 0; r < 4; ++r) inv[r] = 1.0f / lrun[m][r];
    #pragma unroll
    for (int d = 0; d < 4; ++d)
      #pragma unroll
      for (int r = 0; r < 4; ++r) {
        const int row = qw + m * 16 + (lane >> 4) * 4 + r;
        const int col = hh * 64 + d * 16 + (lane & 15);
        aout[(size_t)row * 2048 + col] = f2bf(O[m][d][r] * inv[r]);
      }
  }
}

extern "C" void kernel_launch(void* const* d_in, const int* in_sizes, int n_in,
                              void* d_out, int out_size, void* d_ws, size_t ws_size,
                              hipStream_t stream) {
  (void)in_sizes; (void)n_in; (void)out_size;
  const float* x     = (const float*)d_in[0];
  const float* ln_w  = (const float*)d_in[1];
  const float* ln_b  = (const float*)d_in[2];
  const float* W_in  = (const float*)d_in[3];
  const float* W_out = (const float*)d_in[4];

  const size_t need = 184549376ull;
  if (ws_size < need) return;
  char* ws = (char*)d_ws;
  size_t off = 0;
  uint16_t* h     = (uint16_t*)(ws + off); off += (size_t)2048 * 2048 * 2;
  uint16_t* WtIn  = (uint16_t*)(ws + off); off += (size_t)14336 * 2048 * 2;
  uint16_t* WtOut = (uint16_t*)(ws + off); off += (size_t)2048 * 10240 * 2;
  uint16_t* res   = (uint16_t*)(ws + off); off += (size_t)2048 * 14336 * 2;
  uint16_t* vt    = (uint16_t*)(ws + off); off += (size_t)2048 * 2048 * 2;
  uint16_t* aout  = (uint16_t*)(ws + off);
  float* partials = (float*)ws;  // overlays h+WtIn (dead by GEMM2)

  ln_kernel<<<2048, 256, 0, stream>>>(x, ln_w, ln_b, h);
  transpose_w<<<dim3(224, 32), 256, 0, stream>>>(W_in, WtIn, 2048, 22528, 2048, 0.125f);
  transpose_w<<<dim3(32, 160), 256, 0, stream>>>(W_out, WtOut, 10240, 2048, 0, 1.0f);
  // GEMM1: res = h @ W_in_used (M=2048, N=14336, K=2048) -> bf16
  // 256x256 blocks: grid 8 M x 56 N = 448 blocks of 512 thr (all co-resident)
  gemm_sq<<<dim3(448, 1), 512, 0, stream>>>(h, WtIn, res, 2048, 14336, 64);
  transpose_v<<<dim3(32, 32), 256, 0, stream>>>(res, vt);
  attn_kernel<<<dim3(16, 32), 256, 0, stream>>>(res, vt, aout);
  // GEMM2: out = [aout | res_ffn] @ W_out (M=N=2048, K=10240), split-K=4
  gemm_bw<1, 1><<<dim3(128, 4), 512, 0, stream>>>(aout, res, WtOut, d_out, partials,
                                                  10240, 2048, 2560, 80);
  reduce_add3<<<4096, 256, 0, stream>>>((float*)d_out, partials);
}

// Round 15
// 407.225 us; speedup vs baseline: 1.0727x; 1.0727x over previous
//
#include <hip/hip_runtime.h>
#include <stdint.h>

typedef __bf16 bf16x8 __attribute__((ext_vector_type(8)));
typedef float f32x4 __attribute__((ext_vector_type(4)));
typedef uint16_t u16x4 __attribute__((ext_vector_type(4)));
typedef uint16_t u16x8 __attribute__((ext_vector_type(8)));

#define LOG2E 1.4426950408889634f

__device__ __forceinline__ uint16_t f2bf(float f) {
  union { float f; uint32_t u; } v; v.f = f;
  return (uint16_t)((v.u + 0x7fffu + ((v.u >> 16) & 1u)) >> 16);
}

__device__ __forceinline__ void gload_lds16(const void* g, void* l) {
  __builtin_amdgcn_global_load_lds(
      (const __attribute__((address_space(1))) void*)g,
      (__attribute__((address_space(3))) void*)l, 16, 0, 0);
}

__device__ __forceinline__ f32x4 mfma16(bf16x8 a, bf16x8 b, f32x4 c) {
  return __builtin_amdgcn_mfma_f32_16x16x32_bf16(a, b, c, 0, 0, 0);
}

// ---------------- LayerNorm: x (2048x2048 f32) -> h (bf16) ----------------
__global__ __launch_bounds__(256) void ln_kernel(const float* __restrict__ x,
                                                 const float* __restrict__ g,
                                                 const float* __restrict__ bta,
                                                 uint16_t* __restrict__ h) {
  const int row = blockIdx.x;
  const int t = threadIdx.x;
  const float* xr = x + (size_t)row * 2048 + t * 8;
  float4 v0 = *(const float4*)xr;
  float4 v1 = *(const float4*)(xr + 4);
  float s = v0.x + v0.y + v0.z + v0.w + v1.x + v1.y + v1.z + v1.w;
  float q = v0.x*v0.x + v0.y*v0.y + v0.z*v0.z + v0.w*v0.w
          + v1.x*v1.x + v1.y*v1.y + v1.z*v1.z + v1.w*v1.w;
  #pragma unroll
  for (int m = 1; m < 64; m <<= 1) {
    s += __shfl_xor(s, m);
    q += __shfl_xor(q, m);
  }
  __shared__ float ps[4], pq[4];
  const int wid = t >> 6, lane = t & 63;
  if (lane == 0) { ps[wid] = s; pq[wid] = q; }
  __syncthreads();
  s = ps[0] + ps[1] + ps[2] + ps[3];
  q = pq[0] + pq[1] + pq[2] + pq[3];
  const float mu = s * (1.0f / 2048.0f);
  const float var = q * (1.0f / 2048.0f) - mu * mu;
  const float rs = rsqrtf(var + 1e-5f);
  float4 w0 = *(const float4*)(g + t * 8);
  float4 w1 = *(const float4*)(g + t * 8 + 4);
  float4 b0 = *(const float4*)(bta + t * 8);
  float4 b1 = *(const float4*)(bta + t * 8 + 4);
  u16x8 o;
  o[0] = f2bf((v0.x - mu) * rs * w0.x + b0.x);
  o[1] = f2bf((v0.y - mu) * rs * w0.y + b0.y);
  o[2] = f2bf((v0.z - mu) * rs * w0.z + b0.z);
  o[3] = f2bf((v0.w - mu) * rs * w0.w + b0.w);
  o[4] = f2bf((v1.x - mu) * rs * w1.x + b1.x);
  o[5] = f2bf((v1.y - mu) * rs * w1.y + b1.y);
  o[6] = f2bf((v1.z - mu) * rs * w1.z + b1.z);
  o[7] = f2bf((v1.w - mu) * rs * w1.w + b1.w);
  *(u16x8*)(h + (size_t)row * 2048 + t * 8) = o;
}

// ------- transpose+convert: in (R x ldin f32) -> out (C x R bf16), tile 64x64
__global__ __launch_bounds__(256) void transpose_w(const float* __restrict__ in,
                                                   uint16_t* __restrict__ out,
                                                   int R, int ldin,
                                                   int scale_cols, float scale) {
  __shared__ uint16_t tile[64][65];
  const int c0 = blockIdx.x * 64;
  const int r0 = blockIdx.y * 64;
  const int t = threadIdx.x;
  const int cc = (t & 15) * 4;
  const int rb = t >> 4;
  #pragma unroll
  for (int p = 0; p < 4; ++p) {
    const int r = rb + p * 16;
    const float4 v = *(const float4*)(in + (size_t)(r0 + r) * ldin + c0 + cc);
    const float m0 = (c0 + cc + 0) < scale_cols ? scale : 1.0f;
    const float m1 = (c0 + cc + 1) < scale_cols ? scale : 1.0f;
    const float m2 = (c0 + cc + 2) < scale_cols ? scale : 1.0f;
    const float m3 = (c0 + cc + 3) < scale_cols ? scale : 1.0f;
    tile[r][cc + 0] = f2bf(v.x * m0);
    tile[r][cc + 1] = f2bf(v.y * m1);
    tile[r][cc + 2] = f2bf(v.z * m2);
    tile[r][cc + 3] = f2bf(v.w * m3);
  }
  __syncthreads();
  #pragma unroll
  for (int p = 0; p < 4; ++p) {
    const int oc = rb + p * 16;
    u16x4 ov;
    ov.x = tile[cc + 0][oc];
    ov.y = tile[cc + 1][oc];
    ov.z = tile[cc + 2][oc];
    ov.w = tile[cc + 3][oc];
    *(u16x4*)(out + (size_t)(c0 + oc) * R + r0 + cc) = ov;
  }
}

// ------- transpose V slab of res (cols 4096..6143) -> vt (2048 x 2048 bf16)
__global__ __launch_bounds__(256) void transpose_v(const uint16_t* __restrict__ res,
                                                   uint16_t* __restrict__ vt) {
  __shared__ uint16_t tile[64][65];
  const int c0 = blockIdx.x * 64;
  const int r0 = blockIdx.y * 64;
  const int t = threadIdx.x;
  const int cc = (t & 15) * 4;
  const int rb = t >> 4;
  #pragma unroll
  for (int p = 0; p < 4; ++p) {
    const int r = rb + p * 16;
    const u16x4 v = *(const u16x4*)(res + (size_t)(r0 + r) * 14336 + 4096 + c0 + cc);
    tile[r][cc + 0] = v.x;
    tile[r][cc + 1] = v.y;
    tile[r][cc + 2] = v.z;
    tile[r][cc + 3] = v.w;
  }
  __syncthreads();
  #pragma unroll
  for (int p = 0; p < 4; ++p) {
    const int oc = rb + p * 16;
    u16x4 ov;
    ov.x = tile[cc + 0][oc];
    ov.y = tile[cc + 1][oc];
    ov.z = tile[cc + 2][oc];
    ov.w = tile[cc + 3][oc];
    *(u16x4*)(vt + (size_t)(c0 + oc) * 2048 + r0 + cc) = ov;
  }
}

// ------- Block-wide BT GEMM (r11 best): C(MxN) = A(MxK) * B^T (B: N x K).
// BM=128, BN=256, BK=32, 8 waves (2Mx4N), wave C = 64x64 (acc[4][4]).
// LDS: A 8KB + B 16KB, double-buffered = 48KB -> 2 blocks/CU = 16 waves/CU.
// One vmcnt(0)+barrier per K-tile, stage(t+1) full-tile lead, ds_reads
// compiler-scheduled (fine lgkmcnt), tail sched_barrier pins MFMAs in-tile
// (WAR-safe vs stage overwriting buf^1).
template <int CONCAT, int CF32>
__global__ __launch_bounds__(512, 2) void gemm_bw(
    const uint16_t* __restrict__ A0, const uint16_t* __restrict__ A1,
    const uint16_t* __restrict__ B, void* __restrict__ C0, void* __restrict__ C1,
    int ldbK, int ldc, int kchunk, int nt) {
  __shared__ __attribute__((aligned(16))) uint16_t Alds[2][128 * 32];
  __shared__ __attribute__((aligned(16))) uint16_t Blds[2][256 * 32];
  const int bid = blockIdx.x;
  const int qx = gridDim.x >> 3;
  const int wg = (bid & 7) * qx + (bid >> 3);          // bijective XCD swizzle
  const int m0 = (wg & 15) << 7;                       // 16 M-tiles of 128
  const int n0 = (wg >> 4) << 8;                       // N-tiles of 256
  const int sk = blockIdx.y;
  const int k0 = sk * kchunk;
  const int t = threadIdx.x, wid = t >> 6, lane = t & 63;
  const int wr = wid >> 2, wc = wid & 3;               // 2M x 4N wave grid

  f32x4 acc[4][4] = {};

  auto stage = [&](int tt) {
    const int kg = k0 + tt * 32;
    const uint16_t* As; int lda, kc;
    if (CONCAT && kg >= 2048) { As = A1; lda = 14336; kc = kg + 4096; }
    else                      { As = A0; lda = 2048;  kc = kg; }
    char* ab = (char*)Alds[tt & 1];
    char* bb = (char*)Blds[tt & 1];
    {                                                  // A: 512 x 16B chunks
      const int ch = t;
      const int r = ch >> 2, s = ch & 3;
      gload_lds16(As + (size_t)(m0 + r) * lda + kc + ((s ^ ((r >> 1) & 3)) << 3),
                  ab + ch * 16);
    }
    #pragma unroll
    for (int j = 0; j < 2; ++j) {                      // B: 1024 x 16B chunks
      const int ch = j * 512 + t;
      const int r = ch >> 2, s = ch & 3;
      gload_lds16(B + (size_t)(n0 + r) * ldbK + kg + ((s ^ ((r >> 1) & 3)) << 3),
                  bb + ch * 16);
    }
  };

  stage(0);
  for (int tt = 0; tt < nt; ++tt) {
    const int buf = tt & 1;
    asm volatile("s_waitcnt vmcnt(0)" ::: "memory");   // stage(tt) landed
    __builtin_amdgcn_s_barrier();                      // publish DMA; buf^1 free
    __builtin_amdgcn_sched_barrier(0);
    if (tt + 1 < nt) stage(tt + 1);                    // full-tile lead
    const char* Ab = (const char*)Alds[buf];
    const char* Bb = (const char*)Blds[buf];
    bf16x8 bfr[4], af[4];
    #pragma unroll
    for (int n = 0; n < 4; ++n) {
      const int r = wc * 64 + n * 16 + (lane & 15);
      const int c = (lane >> 4) ^ ((r >> 1) & 3);
      bfr[n] = *(const bf16x8*)(Bb + r * 64 + c * 16);
    }
    #pragma unroll
    for (int m = 0; m < 4; ++m) {
      const int r = wr * 64 + m * 16 + (lane & 15);
      const int c = (lane >> 4) ^ ((r >> 1) & 3);
      af[m] = *(const bf16x8*)(Ab + r * 64 + c * 16);
    }
    #pragma unroll
    for (int m = 0; m < 4; ++m)
      #pragma unroll
      for (int n = 0; n < 4; ++n)
        acc[m][n] = mfma16(af[m], bfr[n], acc[m][n]);
    __builtin_amdgcn_sched_barrier(0);                 // pin MFMAs in-tile
  }

  #pragma unroll
  for (int m = 0; m < 4; ++m)
    #pragma unroll
    for (int n = 0; n < 4; ++n)
      #pragma unroll
      for (int r = 0; r < 4; ++r) {
        const int row = m0 + wr * 64 + m * 16 + (lane >> 4) * 4 + r;
        const int col = n0 + wc * 64 + n * 16 + (lane & 15);
        if (CF32) {
          float* C = (sk == 0) ? (float*)C0
                               : ((float*)C1 + (size_t)(sk - 1) * 4194304ull);
          C[(size_t)row * ldc + col] = acc[m][n][r];
        } else {
          ((uint16_t*)C0)[(size_t)row * ldc + col] = f2bf(acc[m][n][r]);
        }
      }
}

// ------- out += p1 + p2 + p3 (fp32, 2048x2048 each) -------
__global__ __launch_bounds__(256) void reduce_add3(float* __restrict__ out,
                                                   const float* __restrict__ p) {
  const size_t i = ((size_t)blockIdx.x * 256 + threadIdx.x) * 4;
  float4 a = *(const float4*)(out + i);
  const float4 b = *(const float4*)(p + i);
  const float4 c = *(const float4*)(p + 4194304 + i);
  const float4 d = *(const float4*)(p + 8388608 + i);
  a.x += b.x + c.x + d.x;
  a.y += b.y + c.y + d.y;
  a.z += b.z + c.z + d.z;
  a.w += b.w + c.w + d.w;
  *(float4*)(out + i) = a;
}

// ------- causal flash attention, 3-ring K/V pipeline. Block: (xq, head).
// Complement-qt remap for load balance: co-resident pairs get qt and 15-qt.
__global__ __launch_bounds__(256, 2) void attn_kernel(const uint16_t* __restrict__ res,
                                                      const uint16_t* __restrict__ vt,
                                                      uint16_t* __restrict__ aout) {
  const int hh = blockIdx.y;
  const int qt = (hh < 16) ? blockIdx.x : 15 - blockIdx.x;
  const int q0 = qt * 128;
  const int t = threadIdx.x, wid = t >> 6, lane = t & 63;
  const int qw = q0 + wid * 32;
  __shared__ __attribute__((aligned(16))) uint16_t Klds[3][64 * 64];
  __shared__ __attribute__((aligned(16))) uint16_t Vlds[3][64 * 64];
  __shared__ __attribute__((aligned(16))) uint16_t Plds[4 * 32 * 64];
  char* pbase = (char*)Plds + wid * 4096;

  bf16x8 qf[2][2];
  #pragma unroll
  for (int m = 0; m < 2; ++m)
    #pragma unroll
    for (int ks = 0; ks < 2; ++ks)
      qf[m][ks] = *(const bf16x8*)(res + (size_t)(qw + m * 16 + (lane & 15)) * 14336
                                   + hh * 64 + ks * 32 + (lane >> 4) * 8);
  f32x4 O[2][4] = {};
  f32x4 mrun[2], lrun[2];
  #pragma unroll
  for (int m = 0; m < 2; ++m)
    #pragma unroll
    for (int r = 0; r < 4; ++r) { mrun[m][r] = -1e30f; lrun[m][r] = 0.0f; }

  auto stageKV = [&](int kt) {
    const int k0 = kt * 64;
    char* kb = (char*)Klds[kt % 3];
    char* vb = (char*)Vlds[kt % 3];
    #pragma unroll
    for (int i = 0; i < 2; ++i) {
      const int o = (wid * 2 + i) * 1024 + lane * 16;
      const int row = o >> 7;
      const int slot = (o >> 4) & 7;
      const int col = (slot ^ (row & 7)) << 3;
      gload_lds16(res + (size_t)(k0 + row) * 14336 + 2048 + hh * 64 + col,
                  kb + (wid * 2 + i) * 1024);
      gload_lds16(vt + (size_t)(hh * 64 + row) * 2048 + k0 + col,
                  vb + (wid * 2 + i) * 1024);
    }
  };

  const int nkt = qt * 2 + 2;
  stageKV(0);
  if (1 < nkt) stageKV(1);
  for (int kt = 0; kt < nkt; ++kt) {
    const int k0 = kt * 64;
    if (kt + 1 < nkt) { asm volatile("s_waitcnt vmcnt(4)" ::: "memory"); }
    else              { asm volatile("s_waitcnt vmcnt(0)" ::: "memory"); }
    __builtin_amdgcn_s_barrier();
    __builtin_amdgcn_sched_barrier(0);
    if (kt + 2 < nkt) stageKV(kt + 2);
    if (k0 <= qw + 31) {
      const char* Kb = (const char*)Klds[kt % 3];
      const char* Vb = (const char*)Vlds[kt % 3];
      f32x4 s[2][4] = {};
      #pragma unroll
      for (int ks = 0; ks < 2; ++ks) {
        bf16x8 kf[4];
        #pragma unroll
        for (int n = 0; n < 4; ++n) {
          const int row = n * 16 + (lane & 15);
          const int slot = (ks * 4 + (lane >> 4)) ^ (row & 7);
          kf[n] = *(const bf16x8*)(Kb + row * 128 + slot * 16);
        }
        #pragma unroll
        for (int m = 0; m < 2; ++m)
          #pragma unroll
          for (int n = 0; n < 4; ++n)
            s[m][n] = mfma16(qf[m][ks], kf[n], s[m][n]);
      }
      if (k0 + 63 > qw) {
        #pragma unroll
        for (int m = 0; m < 2; ++m)
          #pragma unroll
          for (int n = 0; n < 4; ++n)
            #pragma unroll
            for (int r = 0; r < 4; ++r) {
              const int key = k0 + n * 16 + (lane & 15);
              const int qr = qw + m * 16 + (lane >> 4) * 4 + r;
              if (key > qr) s[m][n][r] = -1e30f;
            }
      }
      #pragma unroll
      for (int m = 0; m < 2; ++m) {
        f32x4 tmax = s[m][0];
        #pragma unroll
        for (int n = 1; n < 4; ++n)
          #pragma unroll
          for (int r = 0; r < 4; ++r) tmax[r] = fmaxf(tmax[r], s[m][n][r]);
        #pragma unroll
        for (int msk = 1; msk < 16; msk <<= 1)
          #pragma unroll
          for (int r = 0; r < 4; ++r) tmax[r] = fmaxf(tmax[r], __shfl_xor(tmax[r], msk));
        f32x4 newm, sc;
        #pragma unroll
        for (int r = 0; r < 4; ++r) {
          newm[r] = fmaxf(mrun[m][r], tmax[r]);
          sc[r] = exp2f((mrun[m][r] - newm[r]) * LOG2E);
          mrun[m][r] = newm[r];
        }
        f32x4 psum;
        #pragma unroll
        for (int r = 0; r < 4; ++r) psum[r] = 0.0f;
        #pragma unroll
        for (int n = 0; n < 4; ++n)
          #pragma unroll
          for (int r = 0; r < 4; ++r) {
            const float p = exp2f((s[m][n][r] - newm[r]) * LOG2E);
            s[m][n][r] = p;
            psum[r] += p;
          }
        #pragma unroll
        for (int msk = 1; msk < 16; msk <<= 1)
          #pragma unroll
          for (int r = 0; r < 4; ++r) psum[r] += __shfl_xor(psum[r], msk);
        #pragma unroll
        for (int r = 0; r < 4; ++r) lrun[m][r] = lrun[m][r] * sc[r] + psum[r];
        #pragma unroll
        for (int d = 0; d < 4; ++d)
          #pragma unroll
          for (int r = 0; r < 4; ++r) O[m][d][r] *= sc[r];
        #pragma unroll
        for (int n = 0; n < 4; ++n)
          #pragma unroll
          for (int r = 0; r < 4; ++r) {
            const int prow = m * 16 + (lane >> 4) * 4 + r;
            const int pcol = n * 16 + (lane & 15);
            *(uint16_t*)(pbase + prow * 128 + (((pcol >> 3) ^ (prow & 7)) << 4)
                         + (pcol & 7) * 2) = f2bf(s[m][n][r]);
          }
      }
      asm volatile("s_waitcnt lgkmcnt(0)" ::: "memory");
      __builtin_amdgcn_sched_barrier(0);
      #pragma unroll
      for (int ks = 0; ks < 2; ++ks) {
        bf16x8 pa[2], vf[4];
        #pragma unroll
        for (int m = 0; m < 2; ++m) {
          const int row = m * 16 + (lane & 15);
          const int slot = (ks * 4 + (lane >> 4)) ^ (row & 7);
          pa[m] = *(const bf16x8*)(pbase + row * 128 + slot * 16);
        }
        #pragma unroll
        for (int d = 0; d < 4; ++d) {
          const int row = d * 16 + (lane & 15);
          const int slot = (ks * 4 + (lane >> 4)) ^ (row & 7);
          vf[d] = *(const bf16x8*)(Vb + row * 128 + slot * 16);
        }
        #pragma unroll
        for (int m = 0; m < 2; ++m)
          #pragma unroll
          for (int d = 0; d < 4; ++d)
            O[m][d] = mfma16(pa[m], vf[d], O[m][d]);
      }
    }
  }
  #pragma unroll
  for (int m = 0; m < 2; ++m) {
    f32x4 inv;
    #pragma unroll
    for (int r = 0; r < 4; ++r) inv[r] = 1.0f / lrun[m][r];
    #pragma unroll
    for (int d = 0; d < 4; ++d)
      #pragma unroll
      for (int r = 0; r < 4; ++r) {
        const int row = qw + m * 16 + (lane >> 4) * 4 + r;
        const int col = hh * 64 + d * 16 + (lane & 15);
        aout[(size_t)row * 2048 + col] = f2bf(O[m][d][r] * inv[r]);
      }
  }
}

extern "C" void kernel_launch(void* const* d_in, const int* in_sizes, int n_in,
                              void* d_out, int out_size, void* d_ws, size_t ws_size,
                              hipStream_t stream) {
  (void)in_sizes; (void)n_in; (void)out_size;
  const float* x     = (const float*)d_in[0];
  const float* ln_w  = (const float*)d_in[1];
  const float* ln_b  = (const float*)d_in[2];
  const float* W_in  = (const float*)d_in[3];
  const float* W_out = (const float*)d_in[4];

  const size_t need = 184549376ull;
  if (ws_size < need) return;
  char* ws = (char*)d_ws;
  size_t off = 0;
  uint16_t* h     = (uint16_t*)(ws + off); off += (size_t)2048 * 2048 * 2;
  uint16_t* WtIn  = (uint16_t*)(ws + off); off += (size_t)14336 * 2048 * 2;
  uint16_t* WtOut = (uint16_t*)(ws + off); off += (size_t)2048 * 10240 * 2;
  uint16_t* res   = (uint16_t*)(ws + off); off += (size_t)2048 * 14336 * 2;
  uint16_t* vt    = (uint16_t*)(ws + off); off += (size_t)2048 * 2048 * 2;
  uint16_t* aout  = (uint16_t*)(ws + off);
  float* partials = (float*)ws;  // overlays h+WtIn (dead by GEMM2)

  ln_kernel<<<2048, 256, 0, stream>>>(x, ln_w, ln_b, h);
  transpose_w<<<dim3(224, 32), 256, 0, stream>>>(W_in, WtIn, 2048, 22528, 2048, 0.125f);
  transpose_w<<<dim3(32, 160), 256, 0, stream>>>(W_out, WtOut, 10240, 2048, 0, 1.0f);
  // GEMM1: res = h @ W_in_used (M=2048, N=14336, K=2048) -> bf16
  gemm_bw<0, 0><<<dim3(896, 1), 512, 0, stream>>>(h, nullptr, WtIn, res, nullptr,
                                                  2048, 14336, 0, 64);
  transpose_v<<<dim3(32, 32), 256, 0, stream>>>(res, vt);
  attn_kernel<<<dim3(16, 32), 256, 0, stream>>>(res, vt, aout);
  // GEMM2: out = [aout | res_ffn] @ W_out (M=N=2048, K=10240), split-K=4
  gemm_bw<1, 1><<<dim3(128, 4), 512, 0, stream>>>(aout, res, WtOut, d_out, partials,
                                                  10240, 2048, 2560, 80);
  reduce_add3<<<4096, 256, 0, stream>>>((float*)d_out, partials);
}

// Round 16
// 402.248 us; speedup vs baseline: 1.0860x; 1.0124x over previous
//
#include <hip/hip_runtime.h>
#include <stdint.h>

typedef __bf16 bf16x8 __attribute__((ext_vector_type(8)));
typedef float f32x4 __attribute__((ext_vector_type(4)));
typedef uint16_t u16x4 __attribute__((ext_vector_type(4)));
typedef uint16_t u16x8 __attribute__((ext_vector_type(8)));

#define LOG2E 1.4426950408889634f

__device__ __forceinline__ uint16_t f2bf(float f) {
  union { float f; uint32_t u; } v; v.f = f;
  return (uint16_t)((v.u + 0x7fffu + ((v.u >> 16) & 1u)) >> 16);
}

__device__ __forceinline__ float bf2f(uint16_t u) {
  union { uint32_t u; float f; } v; v.u = (uint32_t)u << 16;
  return v.f;
}

__device__ __forceinline__ void gload_lds16(const void* g, void* l) {
  __builtin_amdgcn_global_load_lds(
      (const __attribute__((address_space(1))) void*)g,
      (__attribute__((address_space(3))) void*)l, 16, 0, 0);
}

__device__ __forceinline__ f32x4 mfma16(bf16x8 a, bf16x8 b, f32x4 c) {
  return __builtin_amdgcn_mfma_f32_16x16x32_bf16(a, b, c, 0, 0, 0);
}

// ---------------- LayerNorm: x (2048x2048 f32) -> h (bf16) ----------------
__global__ __launch_bounds__(256) void ln_kernel(const float* __restrict__ x,
                                                 const float* __restrict__ g,
                                                 const float* __restrict__ bta,
                                                 uint16_t* __restrict__ h) {
  const int row = blockIdx.x;
  const int t = threadIdx.x;
  const float* xr = x + (size_t)row * 2048 + t * 8;
  float4 v0 = *(const float4*)xr;
  float4 v1 = *(const float4*)(xr + 4);
  float s = v0.x + v0.y + v0.z + v0.w + v1.x + v1.y + v1.z + v1.w;
  float q = v0.x*v0.x + v0.y*v0.y + v0.z*v0.z + v0.w*v0.w
          + v1.x*v1.x + v1.y*v1.y + v1.z*v1.z + v1.w*v1.w;
  #pragma unroll
  for (int m = 1; m < 64; m <<= 1) {
    s += __shfl_xor(s, m);
    q += __shfl_xor(q, m);
  }
  __shared__ float ps[4], pq[4];
  const int wid = t >> 6, lane = t & 63;
  if (lane == 0) { ps[wid] = s; pq[wid] = q; }
  __syncthreads();
  s = ps[0] + ps[1] + ps[2] + ps[3];
  q = pq[0] + pq[1] + pq[2] + pq[3];
  const float mu = s * (1.0f / 2048.0f);
  const float var = q * (1.0f / 2048.0f) - mu * mu;
  const float rs = rsqrtf(var + 1e-5f);
  float4 w0 = *(const float4*)(g + t * 8);
  float4 w1 = *(const float4*)(g + t * 8 + 4);
  float4 b0 = *(const float4*)(bta + t * 8);
  float4 b1 = *(const float4*)(bta + t * 8 + 4);
  u16x8 o;
  o[0] = f2bf((v0.x - mu) * rs * w0.x + b0.x);
  o[1] = f2bf((v0.y - mu) * rs * w0.y + b0.y);
  o[2] = f2bf((v0.z - mu) * rs * w0.z + b0.z);
  o[3] = f2bf((v0.w - mu) * rs * w0.w + b0.w);
  o[4] = f2bf((v1.x - mu) * rs * w1.x + b1.x);
  o[5] = f2bf((v1.y - mu) * rs * w1.y + b1.y);
  o[6] = f2bf((v1.z - mu) * rs * w1.z + b1.z);
  o[7] = f2bf((v1.w - mu) * rs * w1.w + b1.w);
  *(u16x8*)(h + (size_t)row * 2048 + t * 8) = o;
}

// ------- transpose+convert: in (R x ldin f32) -> out (C x R bf16), tile 64x64
__global__ __launch_bounds__(256) void transpose_w(const float* __restrict__ in,
                                                   uint16_t* __restrict__ out,
                                                   int R, int ldin,
                                                   int scale_cols, float scale) {
  __shared__ uint16_t tile[64][65];
  const int c0 = blockIdx.x * 64;
  const int r0 = blockIdx.y * 64;
  const int t = threadIdx.x;
  const int cc = (t & 15) * 4;
  const int rb = t >> 4;
  #pragma unroll
  for (int p = 0; p < 4; ++p) {
    const int r = rb + p * 16;
    const float4 v = *(const float4*)(in + (size_t)(r0 + r) * ldin + c0 + cc);
    const float m0 = (c0 + cc + 0) < scale_cols ? scale : 1.0f;
    const float m1 = (c0 + cc + 1) < scale_cols ? scale : 1.0f;
    const float m2 = (c0 + cc + 2) < scale_cols ? scale : 1.0f;
    const float m3 = (c0 + cc + 3) < scale_cols ? scale : 1.0f;
    tile[r][cc + 0] = f2bf(v.x * m0);
    tile[r][cc + 1] = f2bf(v.y * m1);
    tile[r][cc + 2] = f2bf(v.z * m2);
    tile[r][cc + 3] = f2bf(v.w * m3);
  }
  __syncthreads();
  #pragma unroll
  for (int p = 0; p < 4; ++p) {
    const int oc = rb + p * 16;
    u16x4 ov;
    ov.x = tile[cc + 0][oc];
    ov.y = tile[cc + 1][oc];
    ov.z = tile[cc + 2][oc];
    ov.w = tile[cc + 3][oc];
    *(u16x4*)(out + (size_t)(c0 + oc) * R + r0 + cc) = ov;
  }
}

// ------- transpose V slab of res (cols 4096..6143) -> vt (2048 x 2048 bf16)
__global__ __launch_bounds__(256) void transpose_v(const uint16_t* __restrict__ res,
                                                   uint16_t* __restrict__ vt) {
  __shared__ uint16_t tile[64][65];
  const int c0 = blockIdx.x * 64;
  const int r0 = blockIdx.y * 64;
  const int t = threadIdx.x;
  const int cc = (t & 15) * 4;
  const int rb = t >> 4;
  #pragma unroll
  for (int p = 0; p < 4; ++p) {
    const int r = rb + p * 16;
    const u16x4 v = *(const u16x4*)(res + (size_t)(r0 + r) * 14336 + 4096 + c0 + cc);
    tile[r][cc + 0] = v.x;
    tile[r][cc + 1] = v.y;
    tile[r][cc + 2] = v.z;
    tile[r][cc + 3] = v.w;
  }
  __syncthreads();
  #pragma unroll
  for (int p = 0; p < 4; ++p) {
    const int oc = rb + p * 16;
    u16x4 ov;
    ov.x = tile[cc + 0][oc];
    ov.y = tile[cc + 1][oc];
    ov.z = tile[cc + 2][oc];
    ov.w = tile[cc + 3][oc];
    *(u16x4*)(vt + (size_t)(c0 + oc) * 2048 + r0 + cc) = ov;
  }
}

// ------- Block-wide BT GEMM (r11 best): C(MxN) = A(MxK) * B^T (B: N x K).
// BM=128, BN=256, BK=32, 8 waves (2Mx4N), wave C = 64x64 (acc[4][4]).
// LDS: A 8KB + B 16KB, double-buffered = 48KB -> 2 blocks/CU = 16 waves/CU.
// One vmcnt(0)+barrier per K-tile, stage(t+1) full-tile lead, ds_reads
// compiler-scheduled (fine lgkmcnt), tail sched_barrier pins MFMAs in-tile.
// SPLITK epilogue: sk==0 -> f32 C0; sk>0 -> bf16 partials (half traffic).
template <int CONCAT, int SPLITK>
__global__ __launch_bounds__(512, 2) void gemm_bw(
    const uint16_t* __restrict__ A0, const uint16_t* __restrict__ A1,
    const uint16_t* __restrict__ B, void* __restrict__ C0,
    uint16_t* __restrict__ C1, int ldbK, int ldc, int kchunk, int nt) {
  __shared__ __attribute__((aligned(16))) uint16_t Alds[2][128 * 32];
  __shared__ __attribute__((aligned(16))) uint16_t Blds[2][256 * 32];
  const int bid = blockIdx.x;
  const int qx = gridDim.x >> 3;
  const int wg = (bid & 7) * qx + (bid >> 3);          // bijective XCD swizzle
  const int m0 = (wg & 15) << 7;                       // 16 M-tiles of 128
  const int n0 = (wg >> 4) << 8;                       // N-tiles of 256
  const int sk = blockIdx.y;
  const int k0 = sk * kchunk;
  const int t = threadIdx.x, wid = t >> 6, lane = t & 63;
  const int wr = wid >> 2, wc = wid & 3;               // 2M x 4N wave grid

  f32x4 acc[4][4] = {};

  auto stage = [&](int tt) {
    const int kg = k0 + tt * 32;
    const uint16_t* As; int lda, kc;
    if (CONCAT && kg >= 2048) { As = A1; lda = 14336; kc = kg + 4096; }
    else                      { As = A0; lda = 2048;  kc = kg; }
    char* ab = (char*)Alds[tt & 1];
    char* bb = (char*)Blds[tt & 1];
    {                                                  // A: 512 x 16B chunks
      const int ch = t;
      const int r = ch >> 2, s = ch & 3;
      gload_lds16(As + (size_t)(m0 + r) * lda + kc + ((s ^ ((r >> 1) & 3)) << 3),
                  ab + ch * 16);
    }
    #pragma unroll
    for (int j = 0; j < 2; ++j) {                      // B: 1024 x 16B chunks
      const int ch = j * 512 + t;
      const int r = ch >> 2, s = ch & 3;
      gload_lds16(B + (size_t)(n0 + r) * ldbK + kg + ((s ^ ((r >> 1) & 3)) << 3),
                  bb + ch * 16);
    }
  };

  stage(0);
  for (int tt = 0; tt < nt; ++tt) {
    const int buf = tt & 1;
    asm volatile("s_waitcnt vmcnt(0)" ::: "memory");   // stage(tt) landed
    __builtin_amdgcn_s_barrier();                      // publish DMA; buf^1 free
    __builtin_amdgcn_sched_barrier(0);
    if (tt + 1 < nt) stage(tt + 1);                    // full-tile lead
    const char* Ab = (const char*)Alds[buf];
    const char* Bb = (const char*)Blds[buf];
    bf16x8 bfr[4], af[4];
    #pragma unroll
    for (int n = 0; n < 4; ++n) {
      const int r = wc * 64 + n * 16 + (lane & 15);
      const int c = (lane >> 4) ^ ((r >> 1) & 3);
      bfr[n] = *(const bf16x8*)(Bb + r * 64 + c * 16);
    }
    #pragma unroll
    for (int m = 0; m < 4; ++m) {
      const int r = wr * 64 + m * 16 + (lane & 15);
      const int c = (lane >> 4) ^ ((r >> 1) & 3);
      af[m] = *(const bf16x8*)(Ab + r * 64 + c * 16);
    }
    #pragma unroll
    for (int m = 0; m < 4; ++m)
      #pragma unroll
      for (int n = 0; n < 4; ++n)
        acc[m][n] = mfma16(af[m], bfr[n], acc[m][n]);
    __builtin_amdgcn_sched_barrier(0);                 // pin MFMAs in-tile
  }

  #pragma unroll
  for (int m = 0; m < 4; ++m)
    #pragma unroll
    for (int n = 0; n < 4; ++n)
      #pragma unroll
      for (int r = 0; r < 4; ++r) {
        const int row = m0 + wr * 64 + m * 16 + (lane >> 4) * 4 + r;
        const int col = n0 + wc * 64 + n * 16 + (lane & 15);
        if (SPLITK) {
          if (sk == 0)
            ((float*)C0)[(size_t)row * ldc + col] = acc[m][n][r];
          else
            C1[(size_t)(sk - 1) * 4194304ull + (size_t)row * ldc + col] =
                f2bf(acc[m][n][r]);
        } else {
          ((uint16_t*)C0)[(size_t)row * ldc + col] = f2bf(acc[m][n][r]);
        }
      }
}

// ------- out += p1 + p2 + p3 (bf16 partials, 2048x2048 each) -------
__global__ __launch_bounds__(256) void reduce_add3(float* __restrict__ out,
                                                   const uint16_t* __restrict__ p) {
  const size_t i = ((size_t)blockIdx.x * 256 + threadIdx.x) * 4;
  float4 a = *(const float4*)(out + i);
  const u16x4 b = *(const u16x4*)(p + i);
  const u16x4 c = *(const u16x4*)(p + 4194304 + i);
  const u16x4 d = *(const u16x4*)(p + 8388608 + i);
  a.x += bf2f(b.x) + bf2f(c.x) + bf2f(d.x);
  a.y += bf2f(b.y) + bf2f(c.y) + bf2f(d.y);
  a.z += bf2f(b.z) + bf2f(c.z) + bf2f(d.z);
  a.w += bf2f(b.w) + bf2f(c.w) + bf2f(d.w);
  *(float4*)(out + i) = a;
}

// ------- causal flash attention, 3-ring K/V pipeline. Block: (xq, head).
// Complement-qt remap for load balance: co-resident pairs get qt and 15-qt.
__global__ __launch_bounds__(256, 2) void attn_kernel(const uint16_t* __restrict__ res,
                                                      const uint16_t* __restrict__ vt,
                                                      uint16_t* __restrict__ aout) {
  const int hh = blockIdx.y;
  const int qt = (hh < 16) ? blockIdx.x : 15 - blockIdx.x;
  const int q0 = qt * 128;
  const int t = threadIdx.x, wid = t >> 6, lane = t & 63;
  const int qw = q0 + wid * 32;
  __shared__ __attribute__((aligned(16))) uint16_t Klds[3][64 * 64];
  __shared__ __attribute__((aligned(16))) uint16_t Vlds[3][64 * 64];
  __shared__ __attribute__((aligned(16))) uint16_t Plds[4 * 32 * 64];
  char* pbase = (char*)Plds + wid * 4096;

  bf16x8 qf[2][2];
  #pragma unroll
  for (int m = 0; m < 2; ++m)
    #pragma unroll
    for (int ks = 0; ks < 2; ++ks)
      qf[m][ks] = *(const bf16x8*)(res + (size_t)(qw + m * 16 + (lane & 15)) * 14336
                                   + hh * 64 + ks * 32 + (lane >> 4) * 8);
  f32x4 O[2][4] = {};
  f32x4 mrun[2], lrun[2];
  #pragma unroll
  for (int m = 0; m < 2; ++m)
    #pragma unroll
    for (int r = 0; r < 4; ++r) { mrun[m][r] = -1e30f; lrun[m][r] = 0.0f; }

  auto stageKV = [&](int kt) {
    const int k0 = kt * 64;
    char* kb = (char*)Klds[kt % 3];
    char* vb = (char*)Vlds[kt % 3];
    #pragma unroll
    for (int i = 0; i < 2; ++i) {
      const int o = (wid * 2 + i) * 1024 + lane * 16;
      const int row = o >> 7;
      const int slot = (o >> 4) & 7;
      const int col = (slot ^ (row & 7)) << 3;
      gload_lds16(res + (size_t)(k0 + row) * 14336 + 2048 + hh * 64 + col,
                  kb + (wid * 2 + i) * 1024);
      gload_lds16(vt + (size_t)(hh * 64 + row) * 2048 + k0 + col,
                  vb + (wid * 2 + i) * 1024);
    }
  };

  const int nkt = qt * 2 + 2;
  stageKV(0);
  if (1 < nkt) stageKV(1);
  for (int kt = 0; kt < nkt; ++kt) {
    const int k0 = kt * 64;
    if (kt + 1 < nkt) { asm volatile("s_waitcnt vmcnt(4)" ::: "memory"); }
    else              { asm volatile("s_waitcnt vmcnt(0)" ::: "memory"); }
    __builtin_amdgcn_s_barrier();
    __builtin_amdgcn_sched_barrier(0);
    if (kt + 2 < nkt) stageKV(kt + 2);
    if (k0 <= qw + 31) {
      const char* Kb = (const char*)Klds[kt % 3];
      const char* Vb = (const char*)Vlds[kt % 3];
      f32x4 s[2][4] = {};
      #pragma unroll
      for (int ks = 0; ks < 2; ++ks) {
        bf16x8 kf[4];
        #pragma unroll
        for (int n = 0; n < 4; ++n) {
          const int row = n * 16 + (lane & 15);
          const int slot = (ks * 4 + (lane >> 4)) ^ (row & 7);
          kf[n] = *(const bf16x8*)(Kb + row * 128 + slot * 16);
        }
        #pragma unroll
        for (int m = 0; m < 2; ++m)
          #pragma unroll
          for (int n = 0; n < 4; ++n)
            s[m][n] = mfma16(qf[m][ks], kf[n], s[m][n]);
      }
      if (k0 + 63 > qw) {
        #pragma unroll
        for (int m = 0; m < 2; ++m)
          #pragma unroll
          for (int n = 0; n < 4; ++n)
            #pragma unroll
            for (int r = 0; r < 4; ++r) {
              const int key = k0 + n * 16 + (lane & 15);
              const int qr = qw + m * 16 + (lane >> 4) * 4 + r;
              if (key > qr) s[m][n][r] = -1e30f;
            }
      }
      #pragma unroll
      for (int m = 0; m < 2; ++m) {
        f32x4 tmax = s[m][0];
        #pragma unroll
        for (int n = 1; n < 4; ++n)
          #pragma unroll
          for (int r = 0; r < 4; ++r) tmax[r] = fmaxf(tmax[r], s[m][n][r]);
        #pragma unroll
        for (int msk = 1; msk < 16; msk <<= 1)
          #pragma unroll
          for (int r = 0; r < 4; ++r) tmax[r] = fmaxf(tmax[r], __shfl_xor(tmax[r], msk));
        f32x4 newm, sc;
        #pragma unroll
        for (int r = 0; r < 4; ++r) {
          newm[r] = fmaxf(mrun[m][r], tmax[r]);
          sc[r] = exp2f((mrun[m][r] - newm[r]) * LOG2E);
          mrun[m][r] = newm[r];
        }
        f32x4 psum;
        #pragma unroll
        for (int r = 0; r < 4; ++r) psum[r] = 0.0f;
        #pragma unroll
        for (int n = 0; n < 4; ++n)
          #pragma unroll
          for (int r = 0; r < 4; ++r) {
            const float p = exp2f((s[m][n][r] - newm[r]) * LOG2E);
            s[m][n][r] = p;
            psum[r] += p;
          }
        #pragma unroll
        for (int msk = 1; msk < 16; msk <<= 1)
          #pragma unroll
          for (int r = 0; r < 4; ++r) psum[r] += __shfl_xor(psum[r], msk);
        #pragma unroll
        for (int r = 0; r < 4; ++r) lrun[m][r] = lrun[m][r] * sc[r] + psum[r];
        #pragma unroll
        for (int d = 0; d < 4; ++d)
          #pragma unroll
          for (int r = 0; r < 4; ++r) O[m][d][r] *= sc[r];
        #pragma unroll
        for (int n = 0; n < 4; ++n)
          #pragma unroll
          for (int r = 0; r < 4; ++r) {
            const int prow = m * 16 + (lane >> 4) * 4 + r;
            const int pcol = n * 16 + (lane & 15);
            *(uint16_t*)(pbase + prow * 128 + (((pcol >> 3) ^ (prow & 7)) << 4)
                         + (pcol & 7) * 2) = f2bf(s[m][n][r]);
          }
      }
      asm volatile("s_waitcnt lgkmcnt(0)" ::: "memory");
      __builtin_amdgcn_sched_barrier(0);
      #pragma unroll
      for (int ks = 0; ks < 2; ++ks) {
        bf16x8 pa[2], vf[4];
        #pragma unroll
        for (int m = 0; m < 2; ++m) {
          const int row = m * 16 + (lane & 15);
          const int slot = (ks * 4 + (lane >> 4)) ^ (row & 7);
          pa[m] = *(const bf16x8*)(pbase + row * 128 + slot * 16);
        }
        #pragma unroll
        for (int d = 0; d < 4; ++d) {
          const int row = d * 16 + (lane & 15);
          const int slot = (ks * 4 + (lane >> 4)) ^ (row & 7);
          vf[d] = *(const bf16x8*)(Vb + row * 128 + slot * 16);
        }
        #pragma unroll
        for (int m = 0; m < 2; ++m)
          #pragma unroll
          for (int d = 0; d < 4; ++d)
            O[m][d] = mfma16(pa[m], vf[d], O[m][d]);
      }
    }
  }
  #pragma unroll
  for (int m = 0; m < 2; ++m) {
    f32x4 inv;
    #pragma unroll
    for (int r = 0; r < 4; ++r) inv[r] = 1.0f / lrun[m][r];
    #pragma unroll
    for (int d = 0; d < 4; ++d)
      #pragma unroll
      for (int r = 0; r < 4; ++r) {
        const int row = qw + m * 16 + (lane >> 4) * 4 + r;
        const int col = hh * 64 + d * 16 + (lane & 15);
        aout[(size_t)row * 2048 + col] = f2bf(O[m][d][r] * inv[r]);
      }
  }
}

extern "C" void kernel_launch(void* const* d_in, const int* in_sizes, int n_in,
                              void* d_out, int out_size, void* d_ws, size_t ws_size,
                              hipStream_t stream) {
  (void)in_sizes; (void)n_in; (void)out_size;
  const float* x     = (const float*)d_in[0];
  const float* ln_w  = (const float*)d_in[1];
  const float* ln_b  = (const float*)d_in[2];
  const float* W_in  = (const float*)d_in[3];
  const float* W_out = (const float*)d_in[4];

  const size_t need = 184549376ull;
  if (ws_size < need) return;
  char* ws = (char*)d_ws;
  size_t off = 0;
  uint16_t* h     = (uint16_t*)(ws + off); off += (size_t)2048 * 2048 * 2;
  uint16_t* WtIn  = (uint16_t*)(ws + off); off += (size_t)14336 * 2048 * 2;
  uint16_t* WtOut = (uint16_t*)(ws + off); off += (size_t)2048 * 10240 * 2;
  uint16_t* res   = (uint16_t*)(ws + off); off += (size_t)2048 * 14336 * 2;
  uint16_t* vt    = (uint16_t*)(ws + off); off += (size_t)2048 * 2048 * 2;
  uint16_t* aout  = (uint16_t*)(ws + off);
  uint16_t* partials = (uint16_t*)ws;  // bf16, overlays h+WtIn (dead by GEMM2)

  ln_kernel<<<2048, 256, 0, stream>>>(x, ln_w, ln_b, h);
  transpose_w<<<dim3(224, 32), 256, 0, stream>>>(W_in, WtIn, 2048, 22528, 2048, 0.125f);
  transpose_w<<<dim3(32, 160), 256, 0, stream>>>(W_out, WtOut, 10240, 2048, 0, 1.0f);
  // GEMM1: res = h @ W_in_used (M=2048, N=14336, K=2048) -> bf16
  gemm_bw<0, 0><<<dim3(896, 1), 512, 0, stream>>>(h, nullptr, WtIn, res, nullptr,
                                                  2048, 14336, 0, 64);
  transpose_v<<<dim3(32, 32), 256, 0, stream>>>(res, vt);
  attn_kernel<<<dim3(16, 32), 256, 0, stream>>>(res, vt, aout);
  // GEMM2: out = [aout | res_ffn] @ W_out (M=N=2048, K=10240), split-K=4,
  // sk=0 -> f32 d_out, sk>0 -> bf16 partials
  gemm_bw<1, 1><<<dim3(128, 4), 512, 0, stream>>>(aout, res, WtOut, d_out, partials,
                                                  10240, 2048, 2560, 80);
  reduce_add3<<<4096, 256, 0, stream>>>((float*)d_out, partials);
}